// Round 7
// baseline (847.159 us; speedup 1.0000x reference)
//
#include <hip/hip_runtime.h>

#define TT 2048
#define II 8
#define HH 24
#define THRESH 0.1f
#define LOG2E 1.4426950408889634f

typedef float v2f __attribute__((ext_vector_type(2)));

// rotate within 16-lane row by N, add (DPP row_ror, VALU-only)
#define ROR_ADD(a, N)                                                          \
    {                                                                          \
        int t_ = __builtin_amdgcn_update_dpp(0, __float_as_int(a),             \
                                             0x120 + (N), 0xF, 0xF, false);    \
        (a) += __int_as_float(t_);                                             \
    }

// One wave (= one block) per batch element.
//  lane l32=j<24, lo half : owns gate rows (i_j, f_j) — 2 full 32-wide pk-dots
//  lane l32=j<24, hi half : owns gate rows (g_j, o_j)
//  lanes with l32>=24     : junk (clamped row-0 weights), woutj=0 masks them
// x rows are wave-uniform -> broadcast float4 loads, prefetched 1 step ahead.
// LDS carries only h[24]; single wave -> no __syncthreads (in-order LDS pipe).
// Weights pinned in VGPRs via IN-LOOP empty-asm keep-alives (cannot be
// rematerialized -> must stay loop-carried in registers).
__global__ __launch_bounds__(64, 2)
void lstm_anom_kernel(const float* __restrict__ x,
                      const float* __restrict__ W_ih,
                      const float* __restrict__ W_hh,
                      const float* __restrict__ b_ih,
                      const float* __restrict__ b_hh,
                      const float* __restrict__ W_out,
                      const float* __restrict__ b_out,
                      float* __restrict__ out)
{
    __shared__ __align__(16) float vbuf[32];   // h0..h23 (+pad)

    const int  lane  = threadIdx.x;
    const int  b     = blockIdx.x;
    const int  l32   = lane & 31;
    const bool hi    = lane >= 32;
    const bool unitL = (l32 < HH);
    const int  jc    = unitL ? l32 : 0;        // clamped for junk lanes

    const float* xb = x + (size_t)b * (TT * II);

    // ---- persistent weights: 2 full gate rows per lane, packed f32x2 ----
    const int rowA = (hi ? 2 * HH : 0) + jc;   // lo: i-gate, hi: g-gate
    const int rowB = rowA + HH;                // lo: f-gate, hi: o-gate

    v2f wA2[16], wB2[16];
    {   // W_ih rows (8 floats, 32B-aligned) -> wA2[0..3] / wB2[0..3]
        const float4 a0 = *(const float4*)(W_ih + rowA * II);
        const float4 a1 = *(const float4*)(W_ih + rowA * II + 4);
        const float4 b0 = *(const float4*)(W_ih + rowB * II);
        const float4 b1 = *(const float4*)(W_ih + rowB * II + 4);
        wA2[0] = (v2f){a0.x, a0.y}; wA2[1] = (v2f){a0.z, a0.w};
        wA2[2] = (v2f){a1.x, a1.y}; wA2[3] = (v2f){a1.z, a1.w};
        wB2[0] = (v2f){b0.x, b0.y}; wB2[1] = (v2f){b0.z, b0.w};
        wB2[2] = (v2f){b1.x, b1.y}; wB2[3] = (v2f){b1.z, b1.w};
    }
    #pragma unroll
    for (int q = 0; q < 6; ++q) {  // W_hh rows (24 floats, 96B-aligned base)
        const float4 qa = *(const float4*)(W_hh + rowA * HH + q * 4);
        const float4 qb = *(const float4*)(W_hh + rowB * HH + q * 4);
        wA2[4 + 2 * q]     = (v2f){qa.x, qa.y};
        wA2[4 + 2 * q + 1] = (v2f){qa.z, qa.w};
        wB2[4 + 2 * q]     = (v2f){qb.x, qb.y};
        wB2[4 + 2 * q + 1] = (v2f){qb.z, qb.w};
    }
    float biasA = b_ih[rowA] + b_hh[rowA];
    float biasB = b_ih[rowB] + b_hh[rowB];
    // nonlin A: lo -> sigmoid(a), hi -> tanh(a) = 2*sigmoid(2a)-1, uniform code
    const float kA = hi ? (-2.f * LOG2E) : (-LOG2E);
    const float mA = hi ? 2.f : 1.f;
    const float nA = hi ? -1.f : 0.f;
    const float woutj = unitL ? W_out[jc] : 0.f;
    const float bout  = b_out[0];

    // ---- init v = [x row 0; h0=0], prefetch x row 1 (wave-uniform loads) ----
    v2f v2r[16];
    {
        const float4 q0 = *(const float4*)(xb + 0);
        const float4 q1 = *(const float4*)(xb + 4);
        v2r[0] = (v2f){q0.x, q0.y}; v2r[1] = (v2f){q0.z, q0.w};
        v2r[2] = (v2f){q1.x, q1.y}; v2r[3] = (v2f){q1.z, q1.w};
    }
    #pragma unroll
    for (int k = 4; k < 16; ++k) v2r[k] = (v2f){0.f, 0.f};
    float4 xn0 = *(const float4*)(xb + II);
    float4 xn1 = *(const float4*)(xb + II + 4);

    float pred = v2r[0].x;      // pred0 = x[b][0][0] -> no substitution at t=0
    float cst = 0.f, predsave = 0.f;

    for (int t = 0; t < TT; ++t) {
        // pin weights in registers THIS iteration (defeats load-sinking)
        #pragma unroll
        for (int k = 0; k < 16; ++k) {
            asm volatile("" : "+v"(wA2[k]), "+v"(wB2[k]));
        }
        asm volatile("" : "+v"(biasA), "+v"(biasB));

        // anomaly substitution on input 0 (wave-uniform, in registers)
        v2r[0].x = (fabsf(pred - v2r[0].x) > THRESH) ? pred : v2r[0].x;

        // ---- 2 full 32-wide gate dots per lane, packed FMA ----
        v2f accA = (v2f){biasA, 0.f};
        v2f accB = (v2f){biasB, 0.f};
        #pragma unroll
        for (int k = 0; k < 16; ++k) {
            accA = __builtin_elementwise_fma(wA2[k], v2r[k], accA);
            accB = __builtin_elementwise_fma(wB2[k], v2r[k], accB);
        }
        const float aA = accA.x + accA.y;
        const float aB = accB.x + accB.y;

        // ---- nonlinearities, once per gate ----
        const float sA = __builtin_amdgcn_rcpf(1.f + __builtin_amdgcn_exp2f(kA * aA));
        const float tA = fmaf(sA, mA, nA);                  // lo: sig(i), hi: tanh(g)
        const float sB = __builtin_amdgcn_rcpf(1.f + __builtin_amdgcn_exp2f(-LOG2E * aB));
                                                            // lo: sig(f), hi: sig(o)
        // ---- distribute halves: every lane gets (ig,gg,fg,og) ----
        auto rA = __builtin_amdgcn_permlane32_swap(__float_as_int(tA), __float_as_int(tA), false, false);
        auto rB = __builtin_amdgcn_permlane32_swap(__float_as_int(sB), __float_as_int(sB), false, false);
        const float ig = __int_as_float(rA[0]);
        const float gg = __int_as_float(rA[1]);
        const float fg = __int_as_float(rB[0]);
        const float og = __int_as_float(rB[1]);

        cst = fmaf(fg, cst, ig * gg);
        const float sc = __builtin_amdgcn_rcpf(1.f + __builtin_amdgcn_exp2f(-2.f * LOG2E * cst));
        const float tc = fmaf(2.f, sc, -1.f);               // tanh(c)
        const float h  = og * tc;

        // stage h for next step (banks 0..23, single writer per address)
        if (lane < HH) vbuf[lane] = h;

        // prefetch x row t+2 (wave-uniform); floats freely, no barrier
        int tn = t + 2; if (tn > TT - 1) tn = TT - 1;
        const float4 xp0 = *(const float4*)(xb + (size_t)tn * II);
        const float4 xp1 = *(const float4*)(xb + (size_t)tn * II + 4);

        // ---- head: Σ_j wout_j*h_j (permlane16 fold + 4 DPP ror-adds) ----
        float p = woutj * h;
        {
            auto r = __builtin_amdgcn_permlane16_swap(__float_as_int(p), __float_as_int(p), false, false);
            p = __int_as_float(r[0]) + __int_as_float(r[1]);
        }
        ROR_ADD(p, 8); ROR_ADD(p, 4); ROR_ADD(p, 2); ROR_ADD(p, 1);
        pred = p + bout;

        // buffer pred; coalesced 256B flush every 64 steps
        predsave = ((t & 63) == lane) ? pred : predsave;
        if ((t & 63) == 63) out[(size_t)b * TT + (t - 63) + lane] = predsave;

        // ---- rebuild v for next step: x from prefetch regs, h from LDS ----
        v2r[0] = (v2f){xn0.x, xn0.y}; v2r[1] = (v2f){xn0.z, xn0.w};
        v2r[2] = (v2f){xn1.x, xn1.y}; v2r[3] = (v2f){xn1.z, xn1.w};
        {
            const float4 h0 = *(const float4*)&vbuf[0];
            const float4 h1 = *(const float4*)&vbuf[4];
            const float4 h2 = *(const float4*)&vbuf[8];
            const float4 h3 = *(const float4*)&vbuf[12];
            const float4 h4 = *(const float4*)&vbuf[16];
            const float4 h5 = *(const float4*)&vbuf[20];
            v2r[4]  = (v2f){h0.x, h0.y}; v2r[5]  = (v2f){h0.z, h0.w};
            v2r[6]  = (v2f){h1.x, h1.y}; v2r[7]  = (v2f){h1.z, h1.w};
            v2r[8]  = (v2f){h2.x, h2.y}; v2r[9]  = (v2f){h2.z, h2.w};
            v2r[10] = (v2f){h3.x, h3.y}; v2r[11] = (v2f){h3.z, h3.w};
            v2r[12] = (v2f){h4.x, h4.y}; v2r[13] = (v2f){h4.z, h4.w};
            v2r[14] = (v2f){h5.x, h5.y}; v2r[15] = (v2f){h5.z, h5.w};
        }
        xn0 = xp0; xn1 = xp1;
    }
}

extern "C" void kernel_launch(void* const* d_in, const int* in_sizes, int n_in,
                              void* d_out, int out_size, void* d_ws, size_t ws_size,
                              hipStream_t stream) {
    const float* x     = (const float*)d_in[0];
    const float* W_ih  = (const float*)d_in[1];
    const float* W_hh  = (const float*)d_in[2];
    const float* b_ih  = (const float*)d_in[3];
    const float* b_hh  = (const float*)d_in[4];
    const float* W_out = (const float*)d_in[5];
    const float* b_out = (const float*)d_in[6];
    float* out = (float*)d_out;

    dim3 grid(2048);   // one wave per batch element
    dim3 block(64);
    lstm_anom_kernel<<<grid, block, 0, stream>>>(x, W_ih, W_hh, b_ih, b_hh,
                                                 W_out, b_out, out);
}

// Round 8
// 835.592 us; speedup vs baseline: 1.0138x; 1.0138x over previous
//
#include <hip/hip_runtime.h>

#define TT 2048
#define II 8
#define HH 24
#define THRESH 0.1f
#define LOG2E 1.4426950408889634f

typedef float v2f __attribute__((ext_vector_type(2)));

// rotate within 16-lane row by N, add (DPP row_ror, VALU-only)
#define ROR_ADD(a, N)                                                          \
    {                                                                          \
        int t_ = __builtin_amdgcn_update_dpp(0, __float_as_int(a),             \
                                             0x120 + (N), 0xF, 0xF, false);    \
        (a) += __int_as_float(t_);                                             \
    }

// One wave (= one block) per batch element.
//  lane l32=j<24, lo half : owns gate rows (i_j, f_j) — 2 full 32-wide pk-dots
//  lane l32=j<24, hi half : owns gate rows (g_j, o_j)
//  lanes with l32>=24     : junk (clamped row-0 weights), woutj=0 masks them
// x rows are wave-uniform -> broadcast float4 loads, prefetched 1 step ahead.
// LDS carries only h[24]; single wave -> no __syncthreads (in-order LDS pipe).
//
// amdgpu_waves_per_eu(2,2): grid gives only 2 waves/SIMD (2048 waves/256 CU),
// so tell the scheduler occupancy is pinned at 2 -> 256-VGPR budget -> the
// 64-float weight set stays loop-carried in registers instead of being
// rematerialized from L2 every step (which was an L2-BW roofline: ~34 TB/s).
__global__ __launch_bounds__(64)
__attribute__((amdgpu_waves_per_eu(2, 2)))
void lstm_anom_kernel(const float* __restrict__ x,
                      const float* __restrict__ W_ih,
                      const float* __restrict__ W_hh,
                      const float* __restrict__ b_ih,
                      const float* __restrict__ b_hh,
                      const float* __restrict__ W_out,
                      const float* __restrict__ b_out,
                      float* __restrict__ out)
{
    __shared__ __align__(16) float vbuf[32];   // h0..h23 (+pad)

    const int  lane  = threadIdx.x;
    const int  b     = blockIdx.x;
    const int  l32   = lane & 31;
    const bool hi    = lane >= 32;
    const bool unitL = (l32 < HH);
    const int  jc    = unitL ? l32 : 0;        // clamped for junk lanes

    const float* xb = x + (size_t)b * (TT * II);

    // ---- persistent weights: 2 full gate rows per lane, packed f32x2 ----
    const int rowA = (hi ? 2 * HH : 0) + jc;   // lo: i-gate, hi: g-gate
    const int rowB = rowA + HH;                // lo: f-gate, hi: o-gate

    v2f wA2[16], wB2[16];
    {   // W_ih rows (8 floats, 32B-aligned) -> wA2[0..3] / wB2[0..3]
        const float4 a0 = *(const float4*)(W_ih + rowA * II);
        const float4 a1 = *(const float4*)(W_ih + rowA * II + 4);
        const float4 b0 = *(const float4*)(W_ih + rowB * II);
        const float4 b1 = *(const float4*)(W_ih + rowB * II + 4);
        wA2[0] = (v2f){a0.x, a0.y}; wA2[1] = (v2f){a0.z, a0.w};
        wA2[2] = (v2f){a1.x, a1.y}; wA2[3] = (v2f){a1.z, a1.w};
        wB2[0] = (v2f){b0.x, b0.y}; wB2[1] = (v2f){b0.z, b0.w};
        wB2[2] = (v2f){b1.x, b1.y}; wB2[3] = (v2f){b1.z, b1.w};
    }
    #pragma unroll
    for (int q = 0; q < 6; ++q) {  // W_hh rows (24 floats each)
        const float4 qa = *(const float4*)(W_hh + rowA * HH + q * 4);
        const float4 qb = *(const float4*)(W_hh + rowB * HH + q * 4);
        wA2[4 + 2 * q]     = (v2f){qa.x, qa.y};
        wA2[4 + 2 * q + 1] = (v2f){qa.z, qa.w};
        wB2[4 + 2 * q]     = (v2f){qb.x, qb.y};
        wB2[4 + 2 * q + 1] = (v2f){qb.z, qb.w};
    }
    const float biasA = b_ih[rowA] + b_hh[rowA];
    const float biasB = b_ih[rowB] + b_hh[rowB];
    // nonlin A: lo -> sigmoid(a), hi -> tanh(a) = 2*sigmoid(2a)-1, uniform code
    const float kA = hi ? (-2.f * LOG2E) : (-LOG2E);
    const float mA = hi ? 2.f : 1.f;
    const float nA = hi ? -1.f : 0.f;
    const float woutj = unitL ? W_out[jc] : 0.f;
    const float bout  = b_out[0];

    // ---- init v = [x row 0; h0=0], prefetch x row 1 (wave-uniform loads) ----
    v2f v2r[16];
    {
        const float4 q0 = *(const float4*)(xb + 0);
        const float4 q1 = *(const float4*)(xb + 4);
        v2r[0] = (v2f){q0.x, q0.y}; v2r[1] = (v2f){q0.z, q0.w};
        v2r[2] = (v2f){q1.x, q1.y}; v2r[3] = (v2f){q1.z, q1.w};
    }
    #pragma unroll
    for (int k = 4; k < 16; ++k) v2r[k] = (v2f){0.f, 0.f};
    float4 xn0 = *(const float4*)(xb + II);
    float4 xn1 = *(const float4*)(xb + II + 4);

    float pred = v2r[0].x;      // pred0 = x[b][0][0] -> no substitution at t=0
    float cst = 0.f, predsave = 0.f;

    for (int t = 0; t < TT; ++t) {
        // anomaly substitution on input 0 (wave-uniform, in registers)
        v2r[0].x = (fabsf(pred - v2r[0].x) > THRESH) ? pred : v2r[0].x;

        // ---- 2 full 32-wide gate dots per lane, packed FMA ----
        v2f accA = (v2f){biasA, 0.f};
        v2f accB = (v2f){biasB, 0.f};
        #pragma unroll
        for (int k = 0; k < 16; ++k) {
            accA = __builtin_elementwise_fma(wA2[k], v2r[k], accA);
            accB = __builtin_elementwise_fma(wB2[k], v2r[k], accB);
        }
        const float aA = accA.x + accA.y;
        const float aB = accB.x + accB.y;

        // ---- nonlinearities, once per gate ----
        const float sA = __builtin_amdgcn_rcpf(1.f + __builtin_amdgcn_exp2f(kA * aA));
        const float tA = fmaf(sA, mA, nA);                  // lo: sig(i), hi: tanh(g)
        const float sB = __builtin_amdgcn_rcpf(1.f + __builtin_amdgcn_exp2f(-LOG2E * aB));
                                                            // lo: sig(f), hi: sig(o)
        // ---- distribute halves: every lane gets (ig,gg,fg,og) ----
        auto rA = __builtin_amdgcn_permlane32_swap(__float_as_int(tA), __float_as_int(tA), false, false);
        auto rB = __builtin_amdgcn_permlane32_swap(__float_as_int(sB), __float_as_int(sB), false, false);
        const float ig = __int_as_float(rA[0]);
        const float gg = __int_as_float(rA[1]);
        const float fg = __int_as_float(rB[0]);
        const float og = __int_as_float(rB[1]);

        cst = fmaf(fg, cst, ig * gg);
        const float sc = __builtin_amdgcn_rcpf(1.f + __builtin_amdgcn_exp2f(-2.f * LOG2E * cst));
        const float tc = fmaf(2.f, sc, -1.f);               // tanh(c)
        const float h  = og * tc;

        // stage h for next step (banks 0..23, single writer per address)
        if (lane < HH) vbuf[lane] = h;

        // prefetch x row t+2 (wave-uniform); floats freely, no barrier
        int tn = t + 2; if (tn > TT - 1) tn = TT - 1;
        const float4 xp0 = *(const float4*)(xb + (size_t)tn * II);
        const float4 xp1 = *(const float4*)(xb + (size_t)tn * II + 4);

        // ---- head: Σ_j wout_j*h_j (permlane16 fold + 4 DPP ror-adds) ----
        float p = woutj * h;
        {
            auto r = __builtin_amdgcn_permlane16_swap(__float_as_int(p), __float_as_int(p), false, false);
            p = __int_as_float(r[0]) + __int_as_float(r[1]);
        }
        ROR_ADD(p, 8); ROR_ADD(p, 4); ROR_ADD(p, 2); ROR_ADD(p, 1);
        pred = p + bout;

        // buffer pred; coalesced 256B flush every 64 steps
        predsave = ((t & 63) == lane) ? pred : predsave;
        if ((t & 63) == 63) out[(size_t)b * TT + (t - 63) + lane] = predsave;

        // ---- rebuild v for next step: x from prefetch regs, h from LDS ----
        v2r[0] = (v2f){xn0.x, xn0.y}; v2r[1] = (v2f){xn0.z, xn0.w};
        v2r[2] = (v2f){xn1.x, xn1.y}; v2r[3] = (v2f){xn1.z, xn1.w};
        {
            const float4 h0 = *(const float4*)&vbuf[0];
            const float4 h1 = *(const float4*)&vbuf[4];
            const float4 h2 = *(const float4*)&vbuf[8];
            const float4 h3 = *(const float4*)&vbuf[12];
            const float4 h4 = *(const float4*)&vbuf[16];
            const float4 h5 = *(const float4*)&vbuf[20];
            v2r[4]  = (v2f){h0.x, h0.y}; v2r[5]  = (v2f){h0.z, h0.w};
            v2r[6]  = (v2f){h1.x, h1.y}; v2r[7]  = (v2f){h1.z, h1.w};
            v2r[8]  = (v2f){h2.x, h2.y}; v2r[9]  = (v2f){h2.z, h2.w};
            v2r[10] = (v2f){h3.x, h3.y}; v2r[11] = (v2f){h3.z, h3.w};
            v2r[12] = (v2f){h4.x, h4.y}; v2r[13] = (v2f){h4.z, h4.w};
            v2r[14] = (v2f){h5.x, h5.y}; v2r[15] = (v2f){h5.z, h5.w};
        }
        xn0 = xp0; xn1 = xp1;
    }
}

extern "C" void kernel_launch(void* const* d_in, const int* in_sizes, int n_in,
                              void* d_out, int out_size, void* d_ws, size_t ws_size,
                              hipStream_t stream) {
    const float* x     = (const float*)d_in[0];
    const float* W_ih  = (const float*)d_in[1];
    const float* W_hh  = (const float*)d_in[2];
    const float* b_ih  = (const float*)d_in[3];
    const float* b_hh  = (const float*)d_in[4];
    const float* W_out = (const float*)d_in[5];
    const float* b_out = (const float*)d_in[6];
    float* out = (float*)d_out;

    dim3 grid(2048);   // one wave per batch element
    dim3 block(64);
    lstm_anom_kernel<<<grid, block, 0, stream>>>(x, W_ih, W_hh, b_ih, b_hh,
                                                 W_out, b_out, out);
}

// Round 9
// 728.154 us; speedup vs baseline: 1.1634x; 1.1475x over previous
//
#include <hip/hip_runtime.h>

#define TT 2048
#define II 8
#define HH 24
#define THRESH 0.1f
#define LOG2E 1.4426950408889634f

typedef float v2f __attribute__((ext_vector_type(2)));

// rotate within 16-lane row by N, add (DPP row_ror, VALU-only)
#define ROR_ADD(a, N)                                                          \
    {                                                                          \
        int t_ = __builtin_amdgcn_update_dpp(0, __float_as_int(a),             \
                                             0x120 + (N), 0xF, 0xF, false);    \
        (a) += __int_as_float(t_);                                             \
    }

// One wave (= one block) per batch element.
//  lane l32=j<24, lo half : owns gate rows (i_j, f_j) — 2 full 32-wide pk-dots
//  lane l32=j<24, hi half : owns gate rows (g_j, o_j)
//  lanes 24-31 (lo half)  : x-prefetch lanes (k=0..7), junk weights (clamped)
//  lanes 56-63            : junk (clamped row-0 weights), woutj=0 masks them
//
// KEY (R9): x is loaded by PER-LANE vector loads (vmcnt domain) and staged
// through LDS. No SMEM in the loop -> lgkmcnt is DS-only and precise; the
// x prefetch floats a full step ahead instead of being drained by every
// ds_read wait (R6-R8 regression mechanism: s_load + ds share lgkmcnt).
// Single wave -> no __syncthreads (per-wave LDS pipe is in-order).
__global__ __launch_bounds__(64)
__attribute__((amdgpu_waves_per_eu(2, 2)))
void lstm_anom_kernel(const float* __restrict__ x,
                      const float* __restrict__ W_ih,
                      const float* __restrict__ W_hh,
                      const float* __restrict__ b_ih,
                      const float* __restrict__ b_hh,
                      const float* __restrict__ W_out,
                      const float* __restrict__ b_out,
                      float* __restrict__ out)
{
    __shared__ __align__(16) float vbuf[32];   // [x0..x7; h0..h23]

    const int  lane  = threadIdx.x;
    const int  b     = blockIdx.x;
    const int  l32   = lane & 31;
    const bool hi    = lane >= 32;
    const bool unitL = (l32 < HH);
    const int  jc    = unitL ? l32 : 0;        // clamped for junk lanes
    const bool xL    = (!hi) && (l32 >= 24);   // lanes 24..31
    const int  xk    = l32 - 24;

    const float* xb = x + (size_t)b * (TT * II);

    // ---- persistent weights: 2 full gate rows per lane, packed f32x2 ----
    const int rowA = (hi ? 2 * HH : 0) + jc;   // lo: i-gate, hi: g-gate
    const int rowB = rowA + HH;                // lo: f-gate, hi: o-gate

    v2f wA2[16], wB2[16];
    {   // W_ih rows (8 floats) -> wA2[0..3] / wB2[0..3]
        const float4 a0 = *(const float4*)(W_ih + rowA * II);
        const float4 a1 = *(const float4*)(W_ih + rowA * II + 4);
        const float4 b0 = *(const float4*)(W_ih + rowB * II);
        const float4 b1 = *(const float4*)(W_ih + rowB * II + 4);
        wA2[0] = (v2f){a0.x, a0.y}; wA2[1] = (v2f){a0.z, a0.w};
        wA2[2] = (v2f){a1.x, a1.y}; wA2[3] = (v2f){a1.z, a1.w};
        wB2[0] = (v2f){b0.x, b0.y}; wB2[1] = (v2f){b0.z, b0.w};
        wB2[2] = (v2f){b1.x, b1.y}; wB2[3] = (v2f){b1.z, b1.w};
    }
    #pragma unroll
    for (int q = 0; q < 6; ++q) {  // W_hh rows (24 floats each)
        const float4 qa = *(const float4*)(W_hh + rowA * HH + q * 4);
        const float4 qb = *(const float4*)(W_hh + rowB * HH + q * 4);
        wA2[4 + 2 * q]     = (v2f){qa.x, qa.y};
        wA2[4 + 2 * q + 1] = (v2f){qa.z, qa.w};
        wB2[4 + 2 * q]     = (v2f){qb.x, qb.y};
        wB2[4 + 2 * q + 1] = (v2f){qb.z, qb.w};
    }
    const float biasA = b_ih[rowA] + b_hh[rowA];
    const float biasB = b_ih[rowB] + b_hh[rowB];
    // nonlin A: lo -> sigmoid(a), hi -> tanh(a) = 2*sigmoid(2a)-1, uniform code
    const float kA = hi ? (-2.f * LOG2E) : (-LOG2E);
    const float mA = hi ? 2.f : 1.f;
    const float nA = hi ? -1.f : 0.f;
    const float woutj = unitL ? W_out[jc] : 0.f;
    const float bout  = b_out[0];

    // ---- init: vbuf = [x[b][0][:8]; h0 = 0]; x pipeline in xL lanes ----
    if (lane < 32) vbuf[lane] = (lane < 8) ? xb[lane] : 0.f;
    float xA = 0.f, xB = 0.f;
    if (xL) xA = xb[II + xk];                  // x[b][1][k], per-lane load
    __syncthreads();                           // once, before the loop

    v2f v2r[16];
    #pragma unroll
    for (int c8 = 0; c8 < 8; ++c8) {
        const float4 q = *(const float4*)&vbuf[c8 * 4];
        v2r[c8 * 2]     = (v2f){q.x, q.y};
        v2r[c8 * 2 + 1] = (v2f){q.z, q.w};
    }
    float pred = v2r[0].x;      // pred0 = x[b][0][0] -> no substitution at t=0
    float cst = 0.f, predsave = 0.f;

    for (int t = 0; t < TT; ++t) {
        // anomaly substitution on input 0 (wave-uniform, in registers)
        v2r[0].x = (fabsf(pred - v2r[0].x) > THRESH) ? pred : v2r[0].x;

        // ---- 2 full 32-wide gate dots per lane, packed FMA ----
        v2f accA = (v2f){biasA, 0.f};
        v2f accB = (v2f){biasB, 0.f};
        #pragma unroll
        for (int k = 0; k < 16; ++k) {
            accA = __builtin_elementwise_fma(wA2[k], v2r[k], accA);
            accB = __builtin_elementwise_fma(wB2[k], v2r[k], accB);
        }
        const float aA = accA.x + accA.y;
        const float aB = accB.x + accB.y;

        // ---- nonlinearities, once per gate ----
        const float sA = __builtin_amdgcn_rcpf(1.f + __builtin_amdgcn_exp2f(kA * aA));
        const float tA = fmaf(sA, mA, nA);                  // lo: sig(i), hi: tanh(g)
        const float sB = __builtin_amdgcn_rcpf(1.f + __builtin_amdgcn_exp2f(-LOG2E * aB));
                                                            // lo: sig(f), hi: sig(o)
        // ---- distribute halves: every lane gets (ig,gg,fg,og) ----
        auto rA = __builtin_amdgcn_permlane32_swap(__float_as_int(tA), __float_as_int(tA), false, false);
        auto rB = __builtin_amdgcn_permlane32_swap(__float_as_int(sB), __float_as_int(sB), false, false);
        const float ig = __int_as_float(rA[0]);
        const float gg = __int_as_float(rA[1]);
        const float fg = __int_as_float(rB[0]);
        const float og = __int_as_float(rB[1]);

        cst = fmaf(fg, cst, ig * gg);
        const float sc = __builtin_amdgcn_rcpf(1.f + __builtin_amdgcn_exp2f(-2.f * LOG2E * cst));
        const float tc = fmaf(2.f, sc, -1.f);               // tanh(c)
        const float h  = og * tc;

        // ---- stage next step's inputs: lanes 0-23 write h, 24-31 write x ----
        // banks 0..31 all distinct, conflict-free; same-wave DS pipe is in-order
        if (lane < 32) vbuf[xL ? xk : (8 + l32)] = xL ? xA : h;
        if (xL) {                                // per-lane VECTOR load (vmcnt)
            int tn = t + 2; if (tn > TT - 1) tn = TT - 1;
            xB = xb[(size_t)tn * II + xk];
        }

        // ---- head: Σ_j wout_j*h_j (permlane16 fold + 4 DPP ror-adds) ----
        float p = woutj * h;
        {
            auto r = __builtin_amdgcn_permlane16_swap(__float_as_int(p), __float_as_int(p), false, false);
            p = __int_as_float(r[0]) + __int_as_float(r[1]);
        }
        ROR_ADD(p, 8); ROR_ADD(p, 4); ROR_ADD(p, 2); ROR_ADD(p, 1);
        pred = p + bout;

        // buffer pred; coalesced 256B flush every 64 steps
        predsave = ((t & 63) == lane) ? pred : predsave;
        if ((t & 63) == 63) out[(size_t)b * TT + (t - 63) + lane] = predsave;

        // ---- reload v for next step (broadcast ds_read_b128, DS-only waits)
        #pragma unroll
        for (int c8 = 0; c8 < 8; ++c8) {
            const float4 q = *(const float4*)&vbuf[c8 * 4];
            v2r[c8 * 2]     = (v2f){q.x, q.y};
            v2r[c8 * 2 + 1] = (v2f){q.z, q.w};
        }
        if (xL) xA = xB;
    }
}

extern "C" void kernel_launch(void* const* d_in, const int* in_sizes, int n_in,
                              void* d_out, int out_size, void* d_ws, size_t ws_size,
                              hipStream_t stream) {
    const float* x     = (const float*)d_in[0];
    const float* W_ih  = (const float*)d_in[1];
    const float* W_hh  = (const float*)d_in[2];
    const float* b_ih  = (const float*)d_in[3];
    const float* b_hh  = (const float*)d_in[4];
    const float* W_out = (const float*)d_in[5];
    const float* b_out = (const float*)d_in[6];
    float* out = (float*)d_out;

    dim3 grid(2048);   // one wave per batch element
    dim3 block(64);
    lstm_anom_kernel<<<grid, block, 0, stream>>>(x, W_ih, W_hh, b_ih, b_hh,
                                                 W_out, b_out, out);
}